// Round 7
// baseline (212.263 us; speedup 1.0000x reference)
//
#include <hip/hip_runtime.h>
#include <hip/hip_bf16.h>
#include <math.h>

#define BB 32
#define TT 512
#define SS 128
#define CC 30
#define WW 10
#define DCTX 768
#define DENT 300
#define HH 100
#define EPSF 1e-5f
#define NEGF -1e30f
#define PSTR 320               // proj row stride (bf16 elements), 640 B aligned

typedef __attribute__((ext_vector_type(8))) short bf16x8;
typedef __attribute__((ext_vector_type(4))) float f32x4;

#define NK  (DCTX / 32)        // 24 K-steps
#define NCT 20                 // col-tiles of 16 (320 cols >= 300)

__device__ __forceinline__ float wave_sum(float v) {
    #pragma unroll
    for (int off = 32; off > 0; off >>= 1) v += __shfl_xor(v, off);
    return v;
}

__device__ __forceinline__ ushort f2bf(float f) {
    __hip_bfloat16 h = __float2bfloat16(f);
    return *reinterpret_cast<ushort*>(&h);
}

__device__ __forceinline__ float bf2f1(short s) {
    union { unsigned u; float f; } t;
    t.u = ((unsigned)(unsigned short)s) << 16;
    return t.f;
}
__device__ __forceinline__ void bf8_cvt(bf16x8 v, float4& lo, float4& hi) {
    lo.x = bf2f1(v[0]); lo.y = bf2f1(v[1]); lo.z = bf2f1(v[2]); lo.w = bf2f1(v[3]);
    hi.x = bf2f1(v[4]); hi.y = bf2f1(v[5]); hi.z = bf2f1(v[6]); hi.w = bf2f1(v[7]);
}

__device__ __forceinline__ float dot4(float4 a, float4 b) {
    return a.x*b.x + a.y*b.y + a.z*b.z + a.w*b.w;
}
__device__ __forceinline__ float hadd8(float4 a, float4 b) {
    return a.x+a.y+a.z+a.w + b.x+b.y+b.z+b.w;
}
__device__ __forceinline__ ushort4 cvt4(float4 v) {
    ushort4 h; h.x = f2bf(v.x); h.y = f2bf(v.y); h.z = f2bf(v.z); h.w = f2bf(v.w);
    return h;
}

// ---------------------------------------------------------------------------
// K0: proj_W (300x768 f32) -> frag-major bf16 (zero-padded cols 300..319).
// ---------------------------------------------------------------------------
__global__ __launch_bounds__(256) void wpre_kernel(
    const float* __restrict__ Wt, ushort* __restrict__ wpre)
{
    const int g = blockIdx.x * 256 + threadIdx.x;   // 0 .. NCT*NK*64-1
    const int l = g & 63;
    const int t = (g >> 6) % NK;
    const int ct = g / (NK * 64);
    const int col = ct * 16 + (l & 15);
    const int k = t * 32 + (l >> 4) * 8;
    ushort4 h0 = {0, 0, 0, 0}, h1 = {0, 0, 0, 0};
    if (col < DENT) {
        h0 = cvt4(*(const float4*)(Wt + (size_t)col * DCTX + k));
        h1 = cvt4(*(const float4*)(Wt + (size_t)col * DCTX + k + 4));
    }
    *(ushort4*)(wpre + (size_t)g * 8)     = h0;
    *(ushort4*)(wpre + (size_t)g * 8 + 4) = h1;
}

// ---------------------------------------------------------------------------
// K1: proj(bf16, stride 320) = ctx @ proj_W.T + proj_b  -- hybrid MFMA GEMM
// (R6 core). Cols 300..319 written as exact zeros.
// ---------------------------------------------------------------------------
#define GBM 64
#define LDA 40

__global__ __launch_bounds__(512) void gemm_proj_mfma(
    const float*  __restrict__ A,     // (16384, 768)
    const ushort* __restrict__ wpre,  // frag-major bf16 W
    const float*  __restrict__ bias,  // (300)
    ushort* __restrict__ out)         // (16384, PSTR) bf16
{
    __shared__ ushort Al[2][GBM * LDA];
    const int tid = threadIdx.x;
    const int lane = tid & 63;
    const int wv = tid >> 6;
    const int wm = wv >> 2;          // 0..1
    const int wn = wv & 3;           // 0..3
    const int m0 = blockIdx.x * GBM;
    const int ar = tid >> 3;         // 0..63
    const int ak = (tid & 7) * 4;    // 0..28
    const int lr = lane & 15;
    const int kq = (lane >> 4) * 8;

    const float* aP = A + (size_t)(m0 + ar) * DCTX + ak;
    const ushort* bp = wpre + (size_t)wn * 5 * NK * 512 + (size_t)lane * 8;

    f32x4 acc[2][5];
    #pragma unroll
    for (int i = 0; i < 2; ++i)
        #pragma unroll
        for (int j = 0; j < 5; ++j)
            acc[i][j] = (f32x4){0.f, 0.f, 0.f, 0.f};

    bf16x8 cb[5], nb[5];
    #pragma unroll
    for (int j = 0; j < 5; ++j)
        cb[j] = *(const bf16x8*)(bp + (size_t)j * NK * 512);

#define STOREA(BUF, v_) (*(ushort4*)&Al[BUF][ar * LDA + ak] = cvt4(v_))

#define COMPUTE(BUF) do {                                                      \
        bf16x8 af_[2];                                                         \
        _Pragma("unroll")                                                      \
        for (int i_ = 0; i_ < 2; ++i_)                                         \
            af_[i_] = *(const bf16x8*)&Al[BUF][(wm*32 + i_*16 + lr)*LDA + kq]; \
        _Pragma("unroll")                                                      \
        for (int j_ = 0; j_ < 5; ++j_)                                         \
            acc[0][j_] = __builtin_amdgcn_mfma_f32_16x16x32_bf16(              \
                af_[0], cb[j_], acc[0][j_], 0, 0, 0);                          \
        _Pragma("unroll")                                                      \
        for (int j_ = 0; j_ < 5; ++j_)                                         \
            acc[1][j_] = __builtin_amdgcn_mfma_f32_16x16x32_bf16(              \
                af_[1], cb[j_], acc[1][j_], 0, 0, 0);                          \
    } while (0)

    float4 avA = *(const float4*)(aP);
    float4 avB = *(const float4*)(aP + 32);
    STOREA(0, avA);
    __syncthreads();

    #pragma unroll 1
    for (int kk = 0; kk < NK; kk += 2) {
        #pragma unroll
        for (int j = 0; j < 5; ++j)
            nb[j] = *(const bf16x8*)(bp + ((size_t)j * NK + kk + 1) * 512);
        if (kk + 2 < NK) avA = *(const float4*)(aP + (kk + 2) * 32);
        COMPUTE(0);
        STOREA(1, avB);
        __syncthreads();
        #pragma unroll
        for (int j = 0; j < 5; ++j) cb[j] = nb[j];
        if (kk + 2 < NK) {
            #pragma unroll
            for (int j = 0; j < 5; ++j)
                nb[j] = *(const bf16x8*)(bp + ((size_t)j * NK + kk + 2) * 512);
            avB = *(const float4*)(aP + (kk + 3) * 32);
        }
        COMPUTE(1);
        if (kk + 2 < NK) STOREA(0, avA);
        __syncthreads();
        #pragma unroll
        for (int j = 0; j < 5; ++j) cb[j] = nb[j];
    }

    const int lq = lane >> 4;
    #pragma unroll
    for (int j = 0; j < 5; ++j) {
        int col = wn * 80 + j * 16 + lr;
        float bv = (col < DENT) ? bias[col] : 0.f;   // cols>=300: acc=0,bv=0
        #pragma unroll
        for (int i = 0; i < 2; ++i)
            #pragma unroll
            for (int r = 0; r < 4; ++r) {
                int row = m0 + wm * 32 + i * 16 + lq * 4 + r;
                out[(size_t)row * PSTR + col] = f2bf(acc[i][j][r] + bv);
            }
    }
}

// ---------------------------------------------------------------------------
// K2: FULLY FUSED per-(b,s): span extraction (wave 0, overlapped with the
// other waves' entity gathers) + KG-LN scores + MLP + softmax + weighted sum.
// ---------------------------------------------------------------------------
__global__ __launch_bounds__(512) void final_fused(
    const ushort* __restrict__ proj,    // (B*T, PSTR) bf16
    const int*    __restrict__ spans,   // (B*S, 2)
    const float*  __restrict__ attW,    // (300)
    const float*  __restrict__ attb,    // (1)
    const float*  __restrict__ ln_g,
    const float*  __restrict__ ln_b,
    const float*  __restrict__ kg_g,
    const float*  __restrict__ kg_b,
    const int*    __restrict__ cand,    // (B*S*30)
    const float*  __restrict__ priors,  // (B*S*30)
    const float*  __restrict__ table,   // (V, 300)
    const float*  __restrict__ W1,      // (100,2)
    const float*  __restrict__ b1,      // (100)
    const float*  __restrict__ W2,      // (100)
    const float*  __restrict__ b2,      // (1)
    float* __restrict__ out_link,       // (B*S*30)
    float* __restrict__ out_w)          // (B*S, 300)
{
    __shared__ float rows[CC][DENT];
    __shared__ float s_srg[PSTR];
    __shared__ float smu[CC], srs[CC], ssc[CC], sexp[CC];
    __shared__ float sSG, sSB;
    const int bs = blockIdx.x;
    const int b = bs >> 7;             // SS = 128
    const int tid = threadIdx.x;
    const int lane = tid & 63;
    const int wv = tid >> 6;
    const bool lo = lane < 11;
    const float4 z = make_float4(0.f, 0.f, 0.f, 0.f);

    // ---------- Phase A (all waves): issue entity gathers, stage, s1/s2 ----
    const int c0 = wv, c1 = wv + 8, c2 = wv + 16, c3 = wv + 24;
    const bool has3 = (c3 < CC);
    const int e0 = cand[bs * CC + c0];
    const int e1 = cand[bs * CC + c1];
    const int e2 = cand[bs * CC + c2];
    const int e3 = has3 ? cand[bs * CC + c3] : e2;

    const float4* r0 = (const float4*)(table + (size_t)e0 * DENT);
    const float4* r1 = (const float4*)(table + (size_t)e1 * DENT);
    const float4* r2 = (const float4*)(table + (size_t)e2 * DENT);
    const float4* r3 = (const float4*)(table + (size_t)e3 * DENT);
    float4 xa0 = r0[lane], xa1 = r1[lane], xa2 = r2[lane], xa3 = r3[lane];
    float4 xb0 = lo ? r0[64 + lane] : z;
    float4 xb1 = lo ? r1[64 + lane] : z;
    float4 xb2 = lo ? r2[64 + lane] : z;
    float4 xb3 = lo ? r3[64 + lane] : z;

    *(float4*)&rows[c0][lane * 4] = xa0;
    *(float4*)&rows[c1][lane * 4] = xa1;
    *(float4*)&rows[c2][lane * 4] = xa2;
    if (has3) *(float4*)&rows[c3][lane * 4] = xa3;
    if (lo) {
        *(float4*)&rows[c0][256 + lane * 4] = xb0;
        *(float4*)&rows[c1][256 + lane * 4] = xb1;
        *(float4*)&rows[c2][256 + lane * 4] = xb2;
        if (has3) *(float4*)&rows[c3][256 + lane * 4] = xb3;
    }

    float s1_0 = hadd8(xa0, xb0), s1_1 = hadd8(xa1, xb1);
    float s1_2 = hadd8(xa2, xb2), s1_3 = hadd8(xa3, xb3);
    float s2_0 = dot4(xa0, xa0) + dot4(xb0, xb0), s2_1 = dot4(xa1, xa1) + dot4(xb1, xb1);
    float s2_2 = dot4(xa2, xa2) + dot4(xb2, xb2), s2_3 = dot4(xa3, xa3) + dot4(xb3, xb3);
    #pragma unroll
    for (int off = 32; off > 0; off >>= 1) {
        s1_0 += __shfl_xor(s1_0, off); s1_1 += __shfl_xor(s1_1, off);
        s1_2 += __shfl_xor(s1_2, off); s1_3 += __shfl_xor(s1_3, off);
        s2_0 += __shfl_xor(s2_0, off); s2_1 += __shfl_xor(s2_1, off);
        s2_2 += __shfl_xor(s2_2, off); s2_3 += __shfl_xor(s2_3, off);
    }

    // ---------- Phase B (wave 0): span extraction from bf16 proj ----------
    if (wv == 0) {
        const int start = spans[bs * 2 + 0];
        const int end   = spans[bs * 2 + 1];
        const int width = end - start;
        const bool L   = lane < 40;                 // lanes covering d = lane*8..+7
        const int  dl  = (L ? lane : 39) * 8;
        const bool ga  = L && (dl < DENT);          // first float4 (d<300)
        const bool gb4 = L && (dl + 4 < DENT);      // second float4

        float4 w0v = ga  ? *(const float4*)(attW + dl)     : z;
        float4 w1v = gb4 ? *(const float4*)(attW + dl + 4) : z;

        float slog[WW];
        int rbase[WW];
        bool vld[WW];
        #pragma unroll
        for (int w = 0; w < WW; ++w) {
            int idx = start + w;
            vld[w] = (w <= width) && (idx >= 0) && (idx < TT);
            rbase[w] = (b * TT + (vld[w] ? idx : 0)) * PSTR;
            bf16x8 v = *(const bf16x8*)(proj + rbase[w] + dl);
            float4 plo, phi; bf8_cvt(v, plo, phi);
            if (!L) { plo = z; phi = z; }
            slog[w] = dot4(plo, w0v) + dot4(phi, w1v);
        }
        const float ab = attb[0];
        #pragma unroll
        for (int w = 0; w < WW; ++w) {
            float r = wave_sum(slog[w]);
            slog[w] = vld[w] ? r + ab : NEGF;
        }
        float m = slog[0];
        #pragma unroll
        for (int w = 1; w < WW; ++w) m = fmaxf(m, slog[w]);
        float den = 0.f;
        float aw[WW];
        #pragma unroll
        for (int w = 0; w < WW; ++w) { aw[w] = expf(slog[w] - m); den += aw[w]; }
        const float msk = (start > -1) ? (1.f / den) : 0.f;

        float4 acc0 = z, acc1 = z;
        #pragma unroll
        for (int w = 0; w < WW; ++w) {
            bf16x8 v = *(const bf16x8*)(proj + rbase[w] + dl);   // L1 hit
            float4 plo, phi; bf8_cvt(v, plo, phi);
            if (!L) { plo = z; phi = z; }
            float c = aw[w] * msk;
            acc0.x = fmaf(c, plo.x, acc0.x); acc0.y = fmaf(c, plo.y, acc0.y);
            acc0.z = fmaf(c, plo.z, acc0.z); acc0.w = fmaf(c, plo.w, acc0.w);
            acc1.x = fmaf(c, phi.x, acc1.x); acc1.y = fmaf(c, phi.y, acc1.y);
            acc1.z = fmaf(c, phi.z, acc1.z); acc1.w = fmaf(c, phi.w, acc1.w);
        }
        float s1 = hadd8(acc0, acc1);
        float s2 = dot4(acc0, acc0) + dot4(acc1, acc1);
        #pragma unroll
        for (int off = 32; off > 0; off >>= 1) {
            s1 += __shfl_xor(s1, off);
            s2 += __shfl_xor(s2, off);
        }
        const float mu = s1 * (1.f / DENT);
        const float rstd = rsqrtf(s2 * (1.f / DENT) - mu * mu + EPSF);

        float4 lg0 = ga  ? *(const float4*)(ln_g + dl)     : z;
        float4 lg1 = gb4 ? *(const float4*)(ln_g + dl + 4) : z;
        float4 lb0 = ga  ? *(const float4*)(ln_b + dl)     : z;
        float4 lb1 = gb4 ? *(const float4*)(ln_b + dl + 4) : z;
        float4 gg0 = ga  ? *(const float4*)(kg_g + dl)     : z;
        float4 gg1 = gb4 ? *(const float4*)(kg_g + dl + 4) : z;
        float4 gbv0 = ga  ? *(const float4*)(kg_b + dl)     : z;
        float4 gbv1 = gb4 ? *(const float4*)(kg_b + dl + 4) : z;

        float4 val0, val1, vg0, vg1;
        val0.x = fmaf((acc0.x - mu) * rstd, lg0.x, lb0.x);
        val0.y = fmaf((acc0.y - mu) * rstd, lg0.y, lb0.y);
        val0.z = fmaf((acc0.z - mu) * rstd, lg0.z, lb0.z);
        val0.w = fmaf((acc0.w - mu) * rstd, lg0.w, lb0.w);
        val1.x = fmaf((acc1.x - mu) * rstd, lg1.x, lb1.x);
        val1.y = fmaf((acc1.y - mu) * rstd, lg1.y, lb1.y);
        val1.z = fmaf((acc1.z - mu) * rstd, lg1.z, lb1.z);
        val1.w = fmaf((acc1.w - mu) * rstd, lg1.w, lb1.w);
        vg0 = make_float4(val0.x*gg0.x, val0.y*gg0.y, val0.z*gg0.z, val0.w*gg0.w);
        vg1 = make_float4(val1.x*gg1.x, val1.y*gg1.y, val1.z*gg1.z, val1.w*gg1.w);
        if (L) {
            *(float4*)&s_srg[dl]     = vg0;
            *(float4*)&s_srg[dl + 4] = vg1;
        }
        float pg = hadd8(vg0, vg1);
        float pb = dot4(val0, gbv0) + dot4(val1, gbv1);
        #pragma unroll
        for (int off = 32; off > 0; off >>= 1) {
            pg += __shfl_xor(pg, off);
            pb += __shfl_xor(pb, off);
        }
        if (lane == 0) { sSG = pg; sSB = pb; }
    }
    __syncthreads();

    // ---------- Phase C (all waves): scores + MLP -------------------------
    const float4 g0 = *(const float4*)&s_srg[lane * 4];
    const float4 g1 = lo ? *(const float4*)&s_srg[256 + lane * 4] : z;
    const float SG = sSG;
    const float SB = sSB;

    float s3_0 = dot4(g0, xa0) + dot4(g1, xb0), s3_1 = dot4(g0, xa1) + dot4(g1, xb1);
    float s3_2 = dot4(g0, xa2) + dot4(g1, xb2), s3_3 = dot4(g0, xa3) + dot4(g1, xb3);
    #pragma unroll
    for (int off = 32; off > 0; off >>= 1) {
        s3_0 += __shfl_xor(s3_0, off); s3_1 += __shfl_xor(s3_1, off);
        s3_2 += __shfl_xor(s3_2, off); s3_3 += __shfl_xor(s3_3, off);
    }

    const float W1a0 = W1[2 * lane], W1b0 = W1[2 * lane + 1];
    const float B10 = b1[lane], W20 = W2[lane];
    float W1a1 = 0.f, W1b1 = 0.f, B11 = 0.f, W21 = 0.f;
    if (lane < HH - 64) {
        int j = lane + 64;
        W1a1 = W1[2 * j]; W1b1 = W1[2 * j + 1]; B11 = b1[j]; W21 = W2[j];
    }
    const float b2v = b2[0];
    const float p0 = priors[bs * CC + c0];
    const float p1 = priors[bs * CC + c1];
    const float p2 = priors[bs * CC + c2];
    const float p3 = has3 ? priors[bs * CC + c3] : 0.f;
    const float isd = rsqrtf((float)DENT);

#define CAND_TAIL(K, CK, EK, PK)                                               \
    do {                                                                       \
        float mu_ = s1_##K * (1.f / DENT);                                     \
        float rstd_ = rsqrtf(s2_##K * (1.f / DENT) - mu_ * mu_ + EPSF);        \
        float score_ = (rstd_ * (s3_##K - mu_ * SG) + SB) * isd;               \
        float h_ = fmaxf(fmaf(W1a0, score_, fmaf(W1b0, PK, B10)), 0.f);        \
        float h2_ = fmaxf(fmaf(W1a1, score_, fmaf(W1b1, PK, B11)), 0.f);       \
        float lp_ = fmaf(W21, h2_, W20 * h_);                                  \
        lp_ = wave_sum(lp_) + b2v;                                             \
        float link_ = (EK > 0) ? lp_ : -10000.0f;                              \
        if (lane == 0) {                                                       \
            smu[CK] = mu_; srs[CK] = rstd_; ssc[CK] = link_;                   \
            out_link[bs * CC + CK] = link_;                                    \
        }                                                                      \
    } while (0)

    CAND_TAIL(0, c0, e0, p0);
    CAND_TAIL(1, c1, e1, p1);
    CAND_TAIL(2, c2, e2, p2);
    if (has3) CAND_TAIL(3, c3, e3, p3);
    __syncthreads();

    if (tid < CC) {
        float m = ssc[0];
        #pragma unroll
        for (int c = 1; c < CC; ++c) m = fmaxf(m, ssc[c]);
        sexp[tid] = expf(ssc[tid] - m);
    }
    __syncthreads();

    const int d = tid;
    if (d < DENT) {
        float den = 0.f;
        #pragma unroll
        for (int c = 0; c < CC; ++c) den += sexp[c];
        const float inv = 1.f / den;
        float acc = 0.f, S2 = 0.f, sn = 0.f;
        #pragma unroll
        for (int c = 0; c < CC; ++c) {
            float n = sexp[c] * inv;
            float coef = n * srs[c];
            acc = fmaf(coef, rows[c][d], acc);
            S2 = fmaf(coef, smu[c], S2);
            sn += n;
        }
        out_w[(size_t)bs * DENT + d] = kg_g[d] * (acc - S2) + kg_b[d] * sn;
    }
}

extern "C" void kernel_launch(void* const* d_in, const int* in_sizes, int n_in,
                              void* d_out, int out_size, void* d_ws, size_t ws_size,
                              hipStream_t stream) {
    const float* ctx    = (const float*)d_in[0];
    const int*   spans  = (const int*)d_in[2];
    const int*   cand   = (const int*)d_in[3];
    const float* priors = (const float*)d_in[4];
    const float* table  = (const float*)d_in[6];
    const float* projW  = (const float*)d_in[7];
    const float* projb  = (const float*)d_in[8];
    const float* kg_g   = (const float*)d_in[9];
    const float* kg_b   = (const float*)d_in[10];
    const float* ln_g   = (const float*)d_in[11];
    const float* ln_b   = (const float*)d_in[12];
    const float* attW   = (const float*)d_in[13];
    const float* attb   = (const float*)d_in[14];
    const float* W1     = (const float*)d_in[15];
    const float* b1     = (const float*)d_in[16];
    const float* W2     = (const float*)d_in[17];
    const float* b2     = (const float*)d_in[18];

    ushort* proj = (ushort*)d_ws;                              // (B*T, PSTR) bf16
    ushort* wpre = proj + (size_t)BB * TT * PSTR;              // 492 KB

    float* out_link = (float*)d_out;                           // (B*S*30)
    float* out_w    = out_link + (size_t)BB * SS * CC;         // (B*S, 300)

    wpre_kernel<<<NCT * NK * 64 / 256, 256, 0, stream>>>(projW, wpre);
    gemm_proj_mfma<<<BB * TT / GBM, 512, 0, stream>>>(ctx, wpre, projb, proj);
    final_fused<<<BB * SS, 512, 0, stream>>>(proj, spans, attW, attb,
                                             ln_g, ln_b, kg_g, kg_b,
                                             cand, priors, table,
                                             W1, b1, W2, b2,
                                             out_link, out_w);
}

// Round 8
// 138.506 us; speedup vs baseline: 1.5325x; 1.5325x over previous
//
#include <hip/hip_runtime.h>
#include <hip/hip_bf16.h>
#include <math.h>

#define BB 32
#define TT 512
#define SS 128
#define CC 30
#define WW 10
#define DCTX 768
#define DENT 300
#define HH 100
#define EPSF 1e-5f
#define NEGF -1e30f

typedef __attribute__((ext_vector_type(8))) short bf16x8;
typedef __attribute__((ext_vector_type(4))) float f32x4;

#define NK  (DCTX / 32)        // 24 K-steps
#define NCT 20                 // col-tiles of 16 (320 cols >= 300)

__device__ __forceinline__ float wave_sum(float v) {
    #pragma unroll
    for (int off = 32; off > 0; off >>= 1) v += __shfl_xor(v, off);
    return v;
}

__device__ __forceinline__ ushort f2bf(float f) {
    __hip_bfloat16 h = __float2bfloat16(f);
    return *reinterpret_cast<ushort*>(&h);
}

__device__ __forceinline__ float dot4(float4 a, float4 b) {
    return a.x*b.x + a.y*b.y + a.z*b.z + a.w*b.w;
}
__device__ __forceinline__ float hadd8(float4 a, float4 b) {
    return a.x+a.y+a.z+a.w + b.x+b.y+b.z+b.w;
}
__device__ __forceinline__ ushort4 cvt4(float4 v) {
    ushort4 h; h.x = f2bf(v.x); h.y = f2bf(v.y); h.z = f2bf(v.z); h.w = f2bf(v.w);
    return h;
}

// ---------------------------------------------------------------------------
// K0: proj_W (300x768 f32) -> frag-major bf16 (zero-padded cols 300..319).
// ---------------------------------------------------------------------------
__global__ __launch_bounds__(256) void wpre_kernel(
    const float* __restrict__ Wt, ushort* __restrict__ wpre)
{
    const int g = blockIdx.x * 256 + threadIdx.x;   // 0 .. NCT*NK*64-1
    const int l = g & 63;
    const int t = (g >> 6) % NK;
    const int ct = g / (NK * 64);
    const int col = ct * 16 + (l & 15);
    const int k = t * 32 + (l >> 4) * 8;
    ushort4 h0 = {0, 0, 0, 0}, h1 = {0, 0, 0, 0};
    if (col < DENT) {
        h0 = cvt4(*(const float4*)(Wt + (size_t)col * DCTX + k));
        h1 = cvt4(*(const float4*)(Wt + (size_t)col * DCTX + k + 4));
    }
    *(ushort4*)(wpre + (size_t)g * 8)     = h0;
    *(ushort4*)(wpre + (size_t)g * 8 + 4) = h1;
}

// ---------------------------------------------------------------------------
// K1: proj = ctx @ proj_W.T + proj_b -- hybrid MFMA GEMM (R6, proven).
// A: coalesced f32 -> cvt -> double-buffered LDS, depth-2 reg prefetch.
// B: fragment-direct from frag-major bf16 wpre, depth-1 reg prefetch.
// ---------------------------------------------------------------------------
#define GBM 64
#define LDA 40

__global__ __launch_bounds__(512) void gemm_proj_mfma(
    const float*  __restrict__ A,     // (16384, 768)
    const ushort* __restrict__ wpre,  // frag-major bf16 W
    const float*  __restrict__ bias,  // (300)
    float* __restrict__ out)          // (16384, 300)
{
    __shared__ ushort Al[2][GBM * LDA];
    const int tid = threadIdx.x;
    const int lane = tid & 63;
    const int wv = tid >> 6;
    const int wm = wv >> 2;          // 0..1
    const int wn = wv & 3;           // 0..3
    const int m0 = blockIdx.x * GBM;
    const int ar = tid >> 3;         // 0..63
    const int ak = (tid & 7) * 4;    // 0..28
    const int lr = lane & 15;
    const int kq = (lane >> 4) * 8;

    const float* aP = A + (size_t)(m0 + ar) * DCTX + ak;
    const ushort* bp = wpre + (size_t)wn * 5 * NK * 512 + (size_t)lane * 8;

    f32x4 acc[2][5];
    #pragma unroll
    for (int i = 0; i < 2; ++i)
        #pragma unroll
        for (int j = 0; j < 5; ++j)
            acc[i][j] = (f32x4){0.f, 0.f, 0.f, 0.f};

    bf16x8 cb[5], nb[5];
    #pragma unroll
    for (int j = 0; j < 5; ++j)
        cb[j] = *(const bf16x8*)(bp + (size_t)j * NK * 512);

#define STOREA(BUF, v_) (*(ushort4*)&Al[BUF][ar * LDA + ak] = cvt4(v_))

#define COMPUTE(BUF) do {                                                      \
        bf16x8 af_[2];                                                         \
        _Pragma("unroll")                                                      \
        for (int i_ = 0; i_ < 2; ++i_)                                         \
            af_[i_] = *(const bf16x8*)&Al[BUF][(wm*32 + i_*16 + lr)*LDA + kq]; \
        _Pragma("unroll")                                                      \
        for (int j_ = 0; j_ < 5; ++j_)                                         \
            acc[0][j_] = __builtin_amdgcn_mfma_f32_16x16x32_bf16(              \
                af_[0], cb[j_], acc[0][j_], 0, 0, 0);                          \
        _Pragma("unroll")                                                      \
        for (int j_ = 0; j_ < 5; ++j_)                                         \
            acc[1][j_] = __builtin_amdgcn_mfma_f32_16x16x32_bf16(              \
                af_[1], cb[j_], acc[1][j_], 0, 0, 0);                          \
    } while (0)

    float4 avA = *(const float4*)(aP);
    float4 avB = *(const float4*)(aP + 32);
    STOREA(0, avA);
    __syncthreads();

    #pragma unroll 1
    for (int kk = 0; kk < NK; kk += 2) {
        #pragma unroll
        for (int j = 0; j < 5; ++j)
            nb[j] = *(const bf16x8*)(bp + ((size_t)j * NK + kk + 1) * 512);
        if (kk + 2 < NK) avA = *(const float4*)(aP + (kk + 2) * 32);
        COMPUTE(0);
        STOREA(1, avB);
        __syncthreads();
        #pragma unroll
        for (int j = 0; j < 5; ++j) cb[j] = nb[j];
        if (kk + 2 < NK) {
            #pragma unroll
            for (int j = 0; j < 5; ++j)
                nb[j] = *(const bf16x8*)(bp + ((size_t)j * NK + kk + 2) * 512);
            avB = *(const float4*)(aP + (kk + 3) * 32);
        }
        COMPUTE(1);
        if (kk + 2 < NK) STOREA(0, avA);
        __syncthreads();
        #pragma unroll
        for (int j = 0; j < 5; ++j) cb[j] = nb[j];
    }

    const int lq = lane >> 4;
    #pragma unroll
    for (int j = 0; j < 5; ++j) {
        int col = wn * 80 + j * 16 + lr;
        if (col < DENT) {
            float bv = bias[col];
            #pragma unroll
            for (int i = 0; i < 2; ++i)
                #pragma unroll
                for (int r = 0; r < 4; ++r) {
                    int row = m0 + wm * 32 + i * 16 + lq * 4 + r;
                    out[(size_t)row * DENT + col] = acc[i][j][r] + bv;
                }
        }
    }
}

// ---------------------------------------------------------------------------
// K2: span extraction + LN (R6, proven). 4 spans/block, one wave each.
// ---------------------------------------------------------------------------
__global__ __launch_bounds__(256) void span_kernel(
    const float* __restrict__ proj,     // (B*T, 300)
    const int*   __restrict__ spans,    // (B*S, 2)
    const float* __restrict__ attn_W,   // (300)
    const float* __restrict__ attn_b,   // (1)
    const float* __restrict__ ln_g,
    const float* __restrict__ ln_b,
    const float* __restrict__ kg_g,
    const float* __restrict__ kg_b,
    float* __restrict__ srg_out,        // (B*S, 300)
    float* __restrict__ sgsb)           // (B*S, 2)
{
    const int bs = blockIdx.x * 4 + (threadIdx.x >> 6);
    const int b = bs >> 7;   // SS = 128
    const int lane = threadIdx.x & 63;
    const int start = spans[bs * 2 + 0];
    const int end   = spans[bs * 2 + 1];
    const int width = end - start;
    const bool lo = lane < 11;
    const float4 z = make_float4(0.f, 0.f, 0.f, 0.f);

    const float4* attW4 = (const float4*)attn_W;
    float4 w0 = attW4[lane];
    float4 w1 = lo ? attW4[64 + lane] : z;

    float4 a0[WW], a1[WW];
    float slog[WW];
    bool vld[WW];
    #pragma unroll
    for (int w = 0; w < WW; ++w) {
        int idx = start + w;
        vld[w] = (w <= width) && (idx >= 0) && (idx < TT);
        const float4* pr = (const float4*)(proj + (size_t)(b * TT + (vld[w] ? idx : 0)) * DENT);
        a0[w] = pr[lane];
        a1[w] = lo ? pr[64 + lane] : z;
        slog[w] = dot4(a0[w], w0) + dot4(a1[w], w1);
    }
    const float ab = attn_b[0];
    #pragma unroll
    for (int w = 0; w < WW; ++w) {
        float r = wave_sum(slog[w]);
        slog[w] = vld[w] ? r + ab : NEGF;
    }
    float m = slog[0];
    #pragma unroll
    for (int w = 1; w < WW; ++w) m = fmaxf(m, slog[w]);
    float den = 0.f;
    float aw[WW];
    #pragma unroll
    for (int w = 0; w < WW; ++w) { aw[w] = expf(slog[w] - m); den += aw[w]; }
    const float inv = 1.f / den;
    const float msk = (start > -1) ? inv : 0.f;

    float4 acc0 = z, acc1 = z;
    #pragma unroll
    for (int w = 0; w < WW; ++w) {
        float c = aw[w] * msk;
        acc0.x = fmaf(c, a0[w].x, acc0.x); acc0.y = fmaf(c, a0[w].y, acc0.y);
        acc0.z = fmaf(c, a0[w].z, acc0.z); acc0.w = fmaf(c, a0[w].w, acc0.w);
        acc1.x = fmaf(c, a1[w].x, acc1.x); acc1.y = fmaf(c, a1[w].y, acc1.y);
        acc1.z = fmaf(c, a1[w].z, acc1.z); acc1.w = fmaf(c, a1[w].w, acc1.w);
    }
    float s1 = hadd8(acc0, acc1);
    float s2 = dot4(acc0, acc0) + dot4(acc1, acc1);
    #pragma unroll
    for (int off = 32; off > 0; off >>= 1) {
        s1 += __shfl_xor(s1, off);
        s2 += __shfl_xor(s2, off);
    }
    const float mu = s1 * (1.f / DENT);
    const float rstd = rsqrtf(s2 * (1.f / DENT) - mu * mu + EPSF);

    const float4* lg4 = (const float4*)ln_g;  const float4* lb4 = (const float4*)ln_b;
    const float4* gg4 = (const float4*)kg_g;  const float4* gb4 = (const float4*)kg_b;
    float pg = 0.f, pb = 0.f;
    float4* so = (float4*)(srg_out + (size_t)bs * DENT);
    {
        float4 g = lg4[lane], bb_ = lb4[lane], gg = gg4[lane], gb = gb4[lane];
        float4 val;
        val.x = fmaf((acc0.x - mu) * rstd, g.x, bb_.x);
        val.y = fmaf((acc0.y - mu) * rstd, g.y, bb_.y);
        val.z = fmaf((acc0.z - mu) * rstd, g.z, bb_.z);
        val.w = fmaf((acc0.w - mu) * rstd, g.w, bb_.w);
        float4 vg = make_float4(val.x * gg.x, val.y * gg.y, val.z * gg.z, val.w * gg.w);
        so[lane] = vg;
        pg += vg.x + vg.y + vg.z + vg.w;
        pb += val.x * gb.x + val.y * gb.y + val.z * gb.z + val.w * gb.w;
    }
    if (lo) {
        float4 g = lg4[64 + lane], bb_ = lb4[64 + lane], gg = gg4[64 + lane], gb = gb4[64 + lane];
        float4 val;
        val.x = fmaf((acc1.x - mu) * rstd, g.x, bb_.x);
        val.y = fmaf((acc1.y - mu) * rstd, g.y, bb_.y);
        val.z = fmaf((acc1.z - mu) * rstd, g.z, bb_.z);
        val.w = fmaf((acc1.w - mu) * rstd, g.w, bb_.w);
        float4 vg = make_float4(val.x * gg.x, val.y * gg.y, val.z * gg.z, val.w * gg.w);
        so[64 + lane] = vg;
        pg += vg.x + vg.y + vg.z + vg.w;
        pb += val.x * gb.x + val.y * gb.y + val.z * gb.z + val.w * gb.w;
    }
    #pragma unroll
    for (int off = 32; off > 0; off >>= 1) {
        pg += __shfl_xor(pg, off);
        pb += __shfl_xor(pb, off);
    }
    if (lane == 0) { sgsb[bs * 2 + 0] = pg; sgsb[bs * 2 + 1] = pb; }
}

// ---------------------------------------------------------------------------
// K3: fused scores + softmax + weighted sum, TWO sites per block.
// Site-1's gathers are issued at the top so their HBM latency hides under
// site-0's full processing; site-1 score reductions overlap site-0's
// weighted pass. rows LDS reused serially (barrier-separated).
// ---------------------------------------------------------------------------
__global__ __launch_bounds__(512) void final_fused(
    const float* __restrict__ srg,      // (B*S, 300)
    const float* __restrict__ sgsb,     // (B*S, 2)
    const int*   __restrict__ cand,     // (B*S*30)
    const float* __restrict__ priors,   // (B*S*30)
    const float* __restrict__ table,    // (V, 300)
    const float* __restrict__ W1,       // (100,2)
    const float* __restrict__ b1,       // (100)
    const float* __restrict__ W2,       // (100)
    const float* __restrict__ b2,       // (1)
    const float* __restrict__ kg_g,
    const float* __restrict__ kg_b,
    float* __restrict__ out_link,       // (B*S*30)
    float* __restrict__ out_w)          // (B*S, 300)
{
    __shared__ float rows[CC][DENT];
    __shared__ float smuA[CC], srsA[CC], sscA[CC], sexpA[CC];
    __shared__ float smuB[CC], srsB[CC], sscB[CC], sexpB[CC];
    const int bs0 = blockIdx.x * 2;
    const int bs1 = bs0 + 1;
    const int tid = threadIdx.x;
    const int lane = tid & 63;
    const int wv = tid >> 6;
    const bool lo = lane < 11;
    const float4 z = make_float4(0.f, 0.f, 0.f, 0.f);

    const int c0 = wv, c1 = wv + 8, c2 = wv + 16, c3 = wv + 24;
    const bool has3 = (c3 < CC);

    // ---- issue site-0 gathers first, then site-1 (stays in flight) -------
    const int e00 = cand[bs0 * CC + c0];
    const int e01 = cand[bs0 * CC + c1];
    const int e02 = cand[bs0 * CC + c2];
    const int e03 = has3 ? cand[bs0 * CC + c3] : e02;
    const float4* r00 = (const float4*)(table + (size_t)e00 * DENT);
    const float4* r01 = (const float4*)(table + (size_t)e01 * DENT);
    const float4* r02 = (const float4*)(table + (size_t)e02 * DENT);
    const float4* r03 = (const float4*)(table + (size_t)e03 * DENT);
    float4 p0 = r00[lane], p1 = r01[lane], p2 = r02[lane], p3 = r03[lane];
    float4 q0 = lo ? r00[64 + lane] : z;
    float4 q1 = lo ? r01[64 + lane] : z;
    float4 q2 = lo ? r02[64 + lane] : z;
    float4 q3 = lo ? r03[64 + lane] : z;

    const int e10 = cand[bs1 * CC + c0];
    const int e11 = cand[bs1 * CC + c1];
    const int e12 = cand[bs1 * CC + c2];
    const int e13 = has3 ? cand[bs1 * CC + c3] : e12;
    const float4* r10 = (const float4*)(table + (size_t)e10 * DENT);
    const float4* r11 = (const float4*)(table + (size_t)e11 * DENT);
    const float4* r12 = (const float4*)(table + (size_t)e12 * DENT);
    const float4* r13 = (const float4*)(table + (size_t)e13 * DENT);
    float4 u0 = r10[lane], u1 = r11[lane], u2 = r12[lane], u3 = r13[lane];
    float4 v0 = lo ? r10[64 + lane] : z;
    float4 v1 = lo ? r11[64 + lane] : z;
    float4 v2 = lo ? r12[64 + lane] : z;
    float4 v3 = lo ? r13[64 + lane] : z;

    // ---- shared params (hoisted once) -------------------------------------
    const float4* sg0 = (const float4*)(srg + (size_t)bs0 * DENT);
    float4 g00 = sg0[lane];
    float4 g01 = lo ? sg0[64 + lane] : z;
    const float SG0 = sgsb[bs0 * 2 + 0];
    const float SB0 = sgsb[bs0 * 2 + 1];

    const float W1a0 = W1[2 * lane], W1b0 = W1[2 * lane + 1];
    const float B10 = b1[lane], W20 = W2[lane];
    float W1a1 = 0.f, W1b1 = 0.f, B11 = 0.f, W21 = 0.f;
    if (lane < HH - 64) {
        int j = lane + 64;
        W1a1 = W1[2 * j]; W1b1 = W1[2 * j + 1]; B11 = b1[j]; W21 = W2[j];
    }
    const float b2v = b2[0];
    const float isd = rsqrtf((float)DENT);

#define CAND_TAIL(SMU, SRS, SSC, OUTBS, S1, S2, S3, CK, EK, PK, SG_, SB_)      \
    do {                                                                       \
        float mu_ = S1 * (1.f / DENT);                                         \
        float rstd_ = rsqrtf(S2 * (1.f / DENT) - mu_ * mu_ + EPSF);            \
        float score_ = (rstd_ * (S3 - mu_ * SG_) + SB_) * isd;                 \
        float h_ = fmaxf(fmaf(W1a0, score_, fmaf(W1b0, PK, B10)), 0.f);        \
        float h2_ = fmaxf(fmaf(W1a1, score_, fmaf(W1b1, PK, B11)), 0.f);       \
        float lp_ = fmaf(W21, h2_, W20 * h_);                                  \
        lp_ = wave_sum(lp_) + b2v;                                             \
        float link_ = (EK > 0) ? lp_ : -10000.0f;                              \
        if (lane == 0) {                                                       \
            SMU[CK] = mu_; SRS[CK] = rstd_; SSC[CK] = link_;                   \
            out_link[(OUTBS) * CC + CK] = link_;                               \
        }                                                                      \
    } while (0)

    // ---- site 0: stage + reduce + tails -----------------------------------
    {
        *(float4*)&rows[c0][lane * 4] = p0;
        *(float4*)&rows[c1][lane * 4] = p1;
        *(float4*)&rows[c2][lane * 4] = p2;
        if (has3) *(float4*)&rows[c3][lane * 4] = p3;
        if (lo) {
            *(float4*)&rows[c0][256 + lane * 4] = q0;
            *(float4*)&rows[c1][256 + lane * 4] = q1;
            *(float4*)&rows[c2][256 + lane * 4] = q2;
            if (has3) *(float4*)&rows[c3][256 + lane * 4] = q3;
        }
        float s1_0 = hadd8(p0, q0), s1_1 = hadd8(p1, q1);
        float s1_2 = hadd8(p2, q2), s1_3 = hadd8(p3, q3);
        float s2_0 = dot4(p0, p0) + dot4(q0, q0), s2_1 = dot4(p1, p1) + dot4(q1, q1);
        float s2_2 = dot4(p2, p2) + dot4(q2, q2), s2_3 = dot4(p3, p3) + dot4(q3, q3);
        float s3_0 = dot4(g00, p0) + dot4(g01, q0), s3_1 = dot4(g00, p1) + dot4(g01, q1);
        float s3_2 = dot4(g00, p2) + dot4(g01, q2), s3_3 = dot4(g00, p3) + dot4(g01, q3);
        #pragma unroll
        for (int off = 32; off > 0; off >>= 1) {
            s1_0 += __shfl_xor(s1_0, off); s1_1 += __shfl_xor(s1_1, off);
            s1_2 += __shfl_xor(s1_2, off); s1_3 += __shfl_xor(s1_3, off);
            s2_0 += __shfl_xor(s2_0, off); s2_1 += __shfl_xor(s2_1, off);
            s2_2 += __shfl_xor(s2_2, off); s2_3 += __shfl_xor(s2_3, off);
            s3_0 += __shfl_xor(s3_0, off); s3_1 += __shfl_xor(s3_1, off);
            s3_2 += __shfl_xor(s3_2, off); s3_3 += __shfl_xor(s3_3, off);
        }
        const float pr0 = priors[bs0 * CC + c0];
        const float pr1 = priors[bs0 * CC + c1];
        const float pr2 = priors[bs0 * CC + c2];
        const float pr3 = has3 ? priors[bs0 * CC + c3] : 0.f;
        CAND_TAIL(smuA, srsA, sscA, bs0, s1_0, s2_0, s3_0, c0, e00, pr0, SG0, SB0);
        CAND_TAIL(smuA, srsA, sscA, bs0, s1_1, s2_1, s3_1, c1, e01, pr1, SG0, SB0);
        CAND_TAIL(smuA, srsA, sscA, bs0, s1_2, s2_2, s3_2, c2, e02, pr2, SG0, SB0);
        if (has3)
            CAND_TAIL(smuA, srsA, sscA, bs0, s1_3, s2_3, s3_3, c3, e03, pr3, SG0, SB0);
    }
    __syncthreads();

    if (tid < CC) {
        float m = sscA[0];
        #pragma unroll
        for (int c = 1; c < CC; ++c) m = fmaxf(m, sscA[c]);
        sexpA[tid] = expf(sscA[tid] - m);
    }
    __syncthreads();

    // ---- overlap: site-1 reductions + site-0 weighted pass ----------------
    {
        const float4* sg1 = (const float4*)(srg + (size_t)bs1 * DENT);
        float4 g10 = sg1[lane];
        float4 g11 = lo ? sg1[64 + lane] : z;
        const float SG1 = sgsb[bs1 * 2 + 0];
        const float SB1 = sgsb[bs1 * 2 + 1];
        float s1_0 = hadd8(u0, v0), s1_1 = hadd8(u1, v1);
        float s1_2 = hadd8(u2, v2), s1_3 = hadd8(u3, v3);
        float s2_0 = dot4(u0, u0) + dot4(v0, v0), s2_1 = dot4(u1, u1) + dot4(v1, v1);
        float s2_2 = dot4(u2, u2) + dot4(v2, v2), s2_3 = dot4(u3, u3) + dot4(v3, v3);
        float s3_0 = dot4(g10, u0) + dot4(g11, v0), s3_1 = dot4(g10, u1) + dot4(g11, v1);
        float s3_2 = dot4(g10, u2) + dot4(g11, v2), s3_3 = dot4(g10, u3) + dot4(g11, v3);
        #pragma unroll
        for (int off = 32; off > 0; off >>= 1) {
            s1_0 += __shfl_xor(s1_0, off); s1_1 += __shfl_xor(s1_1, off);
            s1_2 += __shfl_xor(s1_2, off); s1_3 += __shfl_xor(s1_3, off);
            s2_0 += __shfl_xor(s2_0, off); s2_1 += __shfl_xor(s2_1, off);
            s2_2 += __shfl_xor(s2_2, off); s2_3 += __shfl_xor(s2_3, off);
            s3_0 += __shfl_xor(s3_0, off); s3_1 += __shfl_xor(s3_1, off);
            s3_2 += __shfl_xor(s3_2, off); s3_3 += __shfl_xor(s3_3, off);
        }
        const float pr0 = priors[bs1 * CC + c0];
        const float pr1 = priors[bs1 * CC + c1];
        const float pr2 = priors[bs1 * CC + c2];
        const float pr3 = has3 ? priors[bs1 * CC + c3] : 0.f;
        CAND_TAIL(smuB, srsB, sscB, bs1, s1_0, s2_0, s3_0, c0, e10, pr0, SG1, SB1);
        CAND_TAIL(smuB, srsB, sscB, bs1, s1_1, s2_1, s3_1, c1, e11, pr1, SG1, SB1);
        CAND_TAIL(smuB, srsB, sscB, bs1, s1_2, s2_2, s3_2, c2, e12, pr2, SG1, SB1);
        if (has3)
            CAND_TAIL(smuB, srsB, sscB, bs1, s1_3, s2_3, s3_3, c3, e13, pr3, SG1, SB1);
    }
    {
        const int d = tid;
        if (d < DENT) {
            float den = 0.f;
            #pragma unroll
            for (int c = 0; c < CC; ++c) den += sexpA[c];
            const float inv = 1.f / den;
            float acc = 0.f, S2 = 0.f, sn = 0.f;
            #pragma unroll
            for (int c = 0; c < CC; ++c) {
                float n = sexpA[c] * inv;
                float coef = n * srsA[c];
                acc = fmaf(coef, rows[c][d], acc);
                S2 = fmaf(coef, smuA[c], S2);
                sn += n;
            }
            out_w[(size_t)bs0 * DENT + d] = kg_g[d] * (acc - S2) + kg_b[d] * sn;
        }
    }
    __syncthreads();   // all site-0 rows reads done; sscB complete

    // ---- site 1: stage rows + exp -----------------------------------------
    *(float4*)&rows[c0][lane * 4] = u0;
    *(float4*)&rows[c1][lane * 4] = u1;
    *(float4*)&rows[c2][lane * 4] = u2;
    if (has3) *(float4*)&rows[c3][lane * 4] = u3;
    if (lo) {
        *(float4*)&rows[c0][256 + lane * 4] = v0;
        *(float4*)&rows[c1][256 + lane * 4] = v1;
        *(float4*)&rows[c2][256 + lane * 4] = v2;
        if (has3) *(float4*)&rows[c3][256 + lane * 4] = v3;
    }
    if (tid < CC) {
        float m = sscB[0];
        #pragma unroll
        for (int c = 1; c < CC; ++c) m = fmaxf(m, sscB[c]);
        sexpB[tid] = expf(sscB[tid] - m);
    }
    __syncthreads();

    {
        const int d = tid;
        if (d < DENT) {
            float den = 0.f;
            #pragma unroll
            for (int c = 0; c < CC; ++c) den += sexpB[c];
            const float inv = 1.f / den;
            float acc = 0.f, S2 = 0.f, sn = 0.f;
            #pragma unroll
            for (int c = 0; c < CC; ++c) {
                float n = sexpB[c] * inv;
                float coef = n * srsB[c];
                acc = fmaf(coef, rows[c][d], acc);
                S2 = fmaf(coef, smuB[c], S2);
                sn += n;
            }
            out_w[(size_t)bs1 * DENT + d] = kg_g[d] * (acc - S2) + kg_b[d] * sn;
        }
    }
}

extern "C" void kernel_launch(void* const* d_in, const int* in_sizes, int n_in,
                              void* d_out, int out_size, void* d_ws, size_t ws_size,
                              hipStream_t stream) {
    const float* ctx    = (const float*)d_in[0];
    const int*   spans  = (const int*)d_in[2];
    const int*   cand   = (const int*)d_in[3];
    const float* priors = (const float*)d_in[4];
    const float* table  = (const float*)d_in[6];
    const float* projW  = (const float*)d_in[7];
    const float* projb  = (const float*)d_in[8];
    const float* kg_g   = (const float*)d_in[9];
    const float* kg_b   = (const float*)d_in[10];
    const float* ln_g   = (const float*)d_in[11];
    const float* ln_b   = (const float*)d_in[12];
    const float* attW   = (const float*)d_in[13];
    const float* attb   = (const float*)d_in[14];
    const float* W1     = (const float*)d_in[15];
    const float* b1     = (const float*)d_in[16];
    const float* W2     = (const float*)d_in[17];
    const float* b2     = (const float*)d_in[18];

    float* proj = (float*)d_ws;                           // (B*T, 300)
    float* srg  = proj + (size_t)BB * TT * DENT;          // (B*S, 300)
    float* sgsb = srg + (size_t)BB * SS * DENT;           // (B*S, 2)
    // wpre (492 KB) aliases srg: consumed by gemm before span writes srg.
    ushort* wpre = (ushort*)srg;

    float* out_link = (float*)d_out;                      // (B*S*30)
    float* out_w    = out_link + (size_t)BB * SS * CC;    // (B*S, 300)

    wpre_kernel<<<NCT * NK * 64 / 256, 256, 0, stream>>>(projW, wpre);
    gemm_proj_mfma<<<BB * TT / GBM, 512, 0, stream>>>(ctx, wpre, projb, proj);
    span_kernel<<<BB * SS / 4, 256, 0, stream>>>(proj, spans, attW, attb,
                                                 ln_g, ln_b, kg_g, kg_b, srg, sgsb);
    final_fused<<<BB * SS / 2, 512, 0, stream>>>(srg, sgsb, cand, priors, table,
                                                 W1, b1, W2, b2, kg_g, kg_b,
                                                 out_link, out_w);
}

// Round 9
// 81.197 us; speedup vs baseline: 2.6142x; 1.7058x over previous
//
#include <hip/hip_runtime.h>
#include <hip/hip_bf16.h>
#include <math.h>

#define BB 32
#define TT 512
#define SS 128
#define CC 30
#define WW 10
#define DCTX 768
#define DENT 300
#define HH 100
#define EPSF 1e-5f
#define NEGF -1e30f

typedef __attribute__((ext_vector_type(8))) short bf16x8;
typedef __attribute__((ext_vector_type(4))) float f32x4;

#define NK  (DCTX / 32)        // 24 K-steps
#define NCT 20                 // col-tiles of 16 (320 cols >= 300)

// ---- DPP wave64 reduction: 6 VALU ops + readlane, NO DS traffic ----------
template<int C, int M>
__device__ __forceinline__ float dppadd(float x) {
    union { float f; int i; } u, r;
    u.f = x;
    r.i = __builtin_amdgcn_update_dpp(0, u.i, C, M, 0xf, true);
    return x + r.f;
}
__device__ __forceinline__ float wave_red(float x) {
    x = dppadd<0x111, 0xf>(x);   // row_shr:1
    x = dppadd<0x112, 0xf>(x);   // row_shr:2
    x = dppadd<0x114, 0xf>(x);   // row_shr:4
    x = dppadd<0x118, 0xf>(x);   // row_shr:8
    x = dppadd<0x142, 0xa>(x);   // row_bcast:15 -> rows 1,3
    x = dppadd<0x143, 0xc>(x);   // row_bcast:31 -> rows 2,3
    union { float f; int i; } u; u.f = x;
    u.i = __builtin_amdgcn_readlane(u.i, 63);
    return u.f;                  // uniform across the wave
}

__device__ __forceinline__ ushort f2bf(float f) {
    __hip_bfloat16 h = __float2bfloat16(f);
    return *reinterpret_cast<ushort*>(&h);
}

__device__ __forceinline__ float dot4(float4 a, float4 b) {
    return a.x*b.x + a.y*b.y + a.z*b.z + a.w*b.w;
}
__device__ __forceinline__ float hadd8(float4 a, float4 b) {
    return a.x+a.y+a.z+a.w + b.x+b.y+b.z+b.w;
}
__device__ __forceinline__ ushort4 cvt4(float4 v) {
    ushort4 h; h.x = f2bf(v.x); h.y = f2bf(v.y); h.z = f2bf(v.z); h.w = f2bf(v.w);
    return h;
}

// ---------------------------------------------------------------------------
// K0: proj_W (300x768 f32) -> frag-major bf16 (zero-padded cols 300..319).
// ---------------------------------------------------------------------------
__global__ __launch_bounds__(256) void wpre_kernel(
    const float* __restrict__ Wt, ushort* __restrict__ wpre)
{
    const int g = blockIdx.x * 256 + threadIdx.x;   // 0 .. NCT*NK*64-1
    const int l = g & 63;
    const int t = (g >> 6) % NK;
    const int ct = g / (NK * 64);
    const int col = ct * 16 + (l & 15);
    const int k = t * 32 + (l >> 4) * 8;
    ushort4 h0 = {0, 0, 0, 0}, h1 = {0, 0, 0, 0};
    if (col < DENT) {
        h0 = cvt4(*(const float4*)(Wt + (size_t)col * DCTX + k));
        h1 = cvt4(*(const float4*)(Wt + (size_t)col * DCTX + k + 4));
    }
    *(ushort4*)(wpre + (size_t)g * 8)     = h0;
    *(ushort4*)(wpre + (size_t)g * 8 + 4) = h1;
}

// ---------------------------------------------------------------------------
// K1: proj = ctx @ proj_W.T + proj_b -- hybrid MFMA GEMM (R6, proven).
// ---------------------------------------------------------------------------
#define GBM 64
#define LDA 40

__global__ __launch_bounds__(512) void gemm_proj_mfma(
    const float*  __restrict__ A,     // (16384, 768)
    const ushort* __restrict__ wpre,  // frag-major bf16 W
    const float*  __restrict__ bias,  // (300)
    float* __restrict__ out)          // (16384, 300)
{
    __shared__ ushort Al[2][GBM * LDA];
    const int tid = threadIdx.x;
    const int lane = tid & 63;
    const int wv = tid >> 6;
    const int wm = wv >> 2;          // 0..1
    const int wn = wv & 3;           // 0..3
    const int m0 = blockIdx.x * GBM;
    const int ar = tid >> 3;         // 0..63
    const int ak = (tid & 7) * 4;    // 0..28
    const int lr = lane & 15;
    const int kq = (lane >> 4) * 8;

    const float* aP = A + (size_t)(m0 + ar) * DCTX + ak;
    const ushort* bp = wpre + (size_t)wn * 5 * NK * 512 + (size_t)lane * 8;

    f32x4 acc[2][5];
    #pragma unroll
    for (int i = 0; i < 2; ++i)
        #pragma unroll
        for (int j = 0; j < 5; ++j)
            acc[i][j] = (f32x4){0.f, 0.f, 0.f, 0.f};

    bf16x8 cb[5], nb[5];
    #pragma unroll
    for (int j = 0; j < 5; ++j)
        cb[j] = *(const bf16x8*)(bp + (size_t)j * NK * 512);

#define STOREA(BUF, v_) (*(ushort4*)&Al[BUF][ar * LDA + ak] = cvt4(v_))

#define COMPUTE(BUF) do {                                                      \
        bf16x8 af_[2];                                                         \
        _Pragma("unroll")                                                      \
        for (int i_ = 0; i_ < 2; ++i_)                                         \
            af_[i_] = *(const bf16x8*)&Al[BUF][(wm*32 + i_*16 + lr)*LDA + kq]; \
        _Pragma("unroll")                                                      \
        for (int j_ = 0; j_ < 5; ++j_)                                         \
            acc[0][j_] = __builtin_amdgcn_mfma_f32_16x16x32_bf16(              \
                af_[0], cb[j_], acc[0][j_], 0, 0, 0);                          \
        _Pragma("unroll")                                                      \
        for (int j_ = 0; j_ < 5; ++j_)                                         \
            acc[1][j_] = __builtin_amdgcn_mfma_f32_16x16x32_bf16(              \
                af_[1], cb[j_], acc[1][j_], 0, 0, 0);                          \
    } while (0)

    float4 avA = *(const float4*)(aP);
    float4 avB = *(const float4*)(aP + 32);
    STOREA(0, avA);
    __syncthreads();

    #pragma unroll 1
    for (int kk = 0; kk < NK; kk += 2) {
        #pragma unroll
        for (int j = 0; j < 5; ++j)
            nb[j] = *(const bf16x8*)(bp + ((size_t)j * NK + kk + 1) * 512);
        if (kk + 2 < NK) avA = *(const float4*)(aP + (kk + 2) * 32);
        COMPUTE(0);
        STOREA(1, avB);
        __syncthreads();
        #pragma unroll
        for (int j = 0; j < 5; ++j) cb[j] = nb[j];
        if (kk + 2 < NK) {
            #pragma unroll
            for (int j = 0; j < 5; ++j)
                nb[j] = *(const bf16x8*)(bp + ((size_t)j * NK + kk + 2) * 512);
            avB = *(const float4*)(aP + (kk + 3) * 32);
        }
        COMPUTE(1);
        if (kk + 2 < NK) STOREA(0, avA);
        __syncthreads();
        #pragma unroll
        for (int j = 0; j < 5; ++j) cb[j] = nb[j];
    }

    const int lq = lane >> 4;
    #pragma unroll
    for (int j = 0; j < 5; ++j) {
        int col = wn * 80 + j * 16 + lr;
        if (col < DENT) {
            float bv = bias[col];
            #pragma unroll
            for (int i = 0; i < 2; ++i)
                #pragma unroll
                for (int r = 0; r < 4; ++r) {
                    int row = m0 + wm * 32 + i * 16 + lq * 4 + r;
                    out[(size_t)row * DENT + col] = acc[i][j][r] + bv;
                }
        }
    }
}

// ---------------------------------------------------------------------------
// K2: span extraction + LN (R6 structure, DPP reductions). 4 spans/block.
// ---------------------------------------------------------------------------
__global__ __launch_bounds__(256) void span_kernel(
    const float* __restrict__ proj,     // (B*T, 300)
    const int*   __restrict__ spans,    // (B*S, 2)
    const float* __restrict__ attn_W,   // (300)
    const float* __restrict__ attn_b,   // (1)
    const float* __restrict__ ln_g,
    const float* __restrict__ ln_b,
    const float* __restrict__ kg_g,
    const float* __restrict__ kg_b,
    float* __restrict__ srg_out,        // (B*S, 300)
    float* __restrict__ sgsb)           // (B*S, 2)
{
    const int bs = blockIdx.x * 4 + (threadIdx.x >> 6);
    const int b = bs >> 7;   // SS = 128
    const int lane = threadIdx.x & 63;
    const int start = spans[bs * 2 + 0];
    const int end   = spans[bs * 2 + 1];
    const int width = end - start;
    const bool lo = lane < 11;
    const float4 z = make_float4(0.f, 0.f, 0.f, 0.f);

    const float4* attW4 = (const float4*)attn_W;
    float4 w0 = attW4[lane];
    float4 w1 = lo ? attW4[64 + lane] : z;

    float4 a0[WW], a1[WW];
    float slog[WW];
    bool vld[WW];
    #pragma unroll
    for (int w = 0; w < WW; ++w) {
        int idx = start + w;
        vld[w] = (w <= width) && (idx >= 0) && (idx < TT);
        const float4* pr = (const float4*)(proj + (size_t)(b * TT + (vld[w] ? idx : 0)) * DENT);
        a0[w] = pr[lane];
        a1[w] = lo ? pr[64 + lane] : z;
        slog[w] = dot4(a0[w], w0) + dot4(a1[w], w1);
    }
    const float ab = attn_b[0];
    #pragma unroll
    for (int w = 0; w < WW; ++w) {
        float r = wave_red(slog[w]);
        slog[w] = vld[w] ? r + ab : NEGF;
    }
    float m = slog[0];
    #pragma unroll
    for (int w = 1; w < WW; ++w) m = fmaxf(m, slog[w]);
    float den = 0.f;
    float aw[WW];
    #pragma unroll
    for (int w = 0; w < WW; ++w) { aw[w] = expf(slog[w] - m); den += aw[w]; }
    const float inv = 1.f / den;
    const float msk = (start > -1) ? inv : 0.f;

    float4 acc0 = z, acc1 = z;
    #pragma unroll
    for (int w = 0; w < WW; ++w) {
        float c = aw[w] * msk;
        acc0.x = fmaf(c, a0[w].x, acc0.x); acc0.y = fmaf(c, a0[w].y, acc0.y);
        acc0.z = fmaf(c, a0[w].z, acc0.z); acc0.w = fmaf(c, a0[w].w, acc0.w);
        acc1.x = fmaf(c, a1[w].x, acc1.x); acc1.y = fmaf(c, a1[w].y, acc1.y);
        acc1.z = fmaf(c, a1[w].z, acc1.z); acc1.w = fmaf(c, a1[w].w, acc1.w);
    }
    float s1 = wave_red(hadd8(acc0, acc1));
    float s2 = wave_red(dot4(acc0, acc0) + dot4(acc1, acc1));
    const float mu = s1 * (1.f / DENT);
    const float rstd = rsqrtf(s2 * (1.f / DENT) - mu * mu + EPSF);

    const float4* lg4 = (const float4*)ln_g;  const float4* lb4 = (const float4*)ln_b;
    const float4* gg4 = (const float4*)kg_g;  const float4* gb4 = (const float4*)kg_b;
    float pg = 0.f, pb = 0.f;
    float4* so = (float4*)(srg_out + (size_t)bs * DENT);
    {
        float4 g = lg4[lane], bb_ = lb4[lane], gg = gg4[lane], gb = gb4[lane];
        float4 val;
        val.x = fmaf((acc0.x - mu) * rstd, g.x, bb_.x);
        val.y = fmaf((acc0.y - mu) * rstd, g.y, bb_.y);
        val.z = fmaf((acc0.z - mu) * rstd, g.z, bb_.z);
        val.w = fmaf((acc0.w - mu) * rstd, g.w, bb_.w);
        float4 vg = make_float4(val.x * gg.x, val.y * gg.y, val.z * gg.z, val.w * gg.w);
        so[lane] = vg;
        pg += vg.x + vg.y + vg.z + vg.w;
        pb += val.x * gb.x + val.y * gb.y + val.z * gb.z + val.w * gb.w;
    }
    if (lo) {
        float4 g = lg4[64 + lane], bb_ = lb4[64 + lane], gg = gg4[64 + lane], gb = gb4[64 + lane];
        float4 val;
        val.x = fmaf((acc1.x - mu) * rstd, g.x, bb_.x);
        val.y = fmaf((acc1.y - mu) * rstd, g.y, bb_.y);
        val.z = fmaf((acc1.z - mu) * rstd, g.z, bb_.z);
        val.w = fmaf((acc1.w - mu) * rstd, g.w, bb_.w);
        float4 vg = make_float4(val.x * gg.x, val.y * gg.y, val.z * gg.z, val.w * gg.w);
        so[64 + lane] = vg;
        pg += vg.x + vg.y + vg.z + vg.w;
        pb += val.x * gb.x + val.y * gb.y + val.z * gb.z + val.w * gb.w;
    }
    pg = wave_red(pg);
    pb = wave_red(pb);
    if (lane == 0) { sgsb[bs * 2 + 0] = pg; sgsb[bs * 2 + 1] = pb; }
}

// ---------------------------------------------------------------------------
// K3: fused scores + softmax + weighted sum (R6 structure, DPP reductions).
// One block per (b,s), 8 waves; all 4 candidate gathers issued up front.
// ---------------------------------------------------------------------------
__global__ __launch_bounds__(512) void final_fused(
    const float* __restrict__ srg,      // (B*S, 300)
    const float* __restrict__ sgsb,     // (B*S, 2)
    const int*   __restrict__ cand,     // (B*S*30)
    const float* __restrict__ priors,   // (B*S*30)
    const float* __restrict__ table,    // (V, 300)
    const float* __restrict__ W1,       // (100,2)
    const float* __restrict__ b1,       // (100)
    const float* __restrict__ W2,       // (100)
    const float* __restrict__ b2,       // (1)
    const float* __restrict__ kg_g,
    const float* __restrict__ kg_b,
    float* __restrict__ out_link,       // (B*S*30)
    float* __restrict__ out_w)          // (B*S, 300)
{
    __shared__ float rows[CC][DENT];
    __shared__ float smu[CC], srs[CC], ssc[CC], sexp[CC];
    const int bs = blockIdx.x;
    const int tid = threadIdx.x;
    const int lane = tid & 63;
    const int wv = tid >> 6;
    const bool lo = lane < 11;
    const float4 z = make_float4(0.f, 0.f, 0.f, 0.f);

    const int c0 = wv, c1 = wv + 8, c2 = wv + 16, c3 = wv + 24;
    const bool has3 = (c3 < CC);
    const int e0 = cand[bs * CC + c0];
    const int e1 = cand[bs * CC + c1];
    const int e2 = cand[bs * CC + c2];
    const int e3 = has3 ? cand[bs * CC + c3] : e2;

    const float4* r0 = (const float4*)(table + (size_t)e0 * DENT);
    const float4* r1 = (const float4*)(table + (size_t)e1 * DENT);
    const float4* r2 = (const float4*)(table + (size_t)e2 * DENT);
    const float4* r3 = (const float4*)(table + (size_t)e3 * DENT);
    float4 xa0 = r0[lane], xa1 = r1[lane], xa2 = r2[lane], xa3 = r3[lane];
    float4 xb0 = lo ? r0[64 + lane] : z;
    float4 xb1 = lo ? r1[64 + lane] : z;
    float4 xb2 = lo ? r2[64 + lane] : z;
    float4 xb3 = lo ? r3[64 + lane] : z;

    const float4* sg4 = (const float4*)(srg + (size_t)bs * DENT);
    float4 g0 = sg4[lane];
    float4 g1 = lo ? sg4[64 + lane] : z;
    const float SG = sgsb[bs * 2 + 0];
    const float SB = sgsb[bs * 2 + 1];

    const float W1a0 = W1[2 * lane], W1b0 = W1[2 * lane + 1];
    const float B10 = b1[lane], W20 = W2[lane];
    float W1a1 = 0.f, W1b1 = 0.f, B11 = 0.f, W21 = 0.f;
    if (lane < HH - 64) {
        int j = lane + 64;
        W1a1 = W1[2 * j]; W1b1 = W1[2 * j + 1]; B11 = b1[j]; W21 = W2[j];
    }
    const float b2v = b2[0];
    const float p0 = priors[bs * CC + c0];
    const float p1 = priors[bs * CC + c1];
    const float p2 = priors[bs * CC + c2];
    const float p3 = has3 ? priors[bs * CC + c3] : 0.f;

    *(float4*)&rows[c0][lane * 4] = xa0;
    *(float4*)&rows[c1][lane * 4] = xa1;
    *(float4*)&rows[c2][lane * 4] = xa2;
    if (has3) *(float4*)&rows[c3][lane * 4] = xa3;
    if (lo) {
        *(float4*)&rows[c0][256 + lane * 4] = xb0;
        *(float4*)&rows[c1][256 + lane * 4] = xb1;
        *(float4*)&rows[c2][256 + lane * 4] = xb2;
        if (has3) *(float4*)&rows[c3][256 + lane * 4] = xb3;
    }

    // 12 independent DPP reduce chains (VALU pipe, no DS)
    float s1_0 = wave_red(hadd8(xa0, xb0));
    float s1_1 = wave_red(hadd8(xa1, xb1));
    float s1_2 = wave_red(hadd8(xa2, xb2));
    float s1_3 = wave_red(hadd8(xa3, xb3));
    float s2_0 = wave_red(dot4(xa0, xa0) + dot4(xb0, xb0));
    float s2_1 = wave_red(dot4(xa1, xa1) + dot4(xb1, xb1));
    float s2_2 = wave_red(dot4(xa2, xa2) + dot4(xb2, xb2));
    float s2_3 = wave_red(dot4(xa3, xa3) + dot4(xb3, xb3));
    float s3_0 = wave_red(dot4(g0, xa0) + dot4(g1, xb0));
    float s3_1 = wave_red(dot4(g0, xa1) + dot4(g1, xb1));
    float s3_2 = wave_red(dot4(g0, xa2) + dot4(g1, xb2));
    float s3_3 = wave_red(dot4(g0, xa3) + dot4(g1, xb3));
    const float isd = rsqrtf((float)DENT);

#define CAND_TAIL(K, CK, EK, PK)                                               \
    do {                                                                       \
        float mu_ = s1_##K * (1.f / DENT);                                     \
        float rstd_ = rsqrtf(s2_##K * (1.f / DENT) - mu_ * mu_ + EPSF);        \
        float score_ = (rstd_ * (s3_##K - mu_ * SG) + SB) * isd;               \
        float h_ = fmaxf(fmaf(W1a0, score_, fmaf(W1b0, PK, B10)), 0.f);        \
        float h2_ = fmaxf(fmaf(W1a1, score_, fmaf(W1b1, PK, B11)), 0.f);       \
        float lp_ = fmaf(W21, h2_, W20 * h_);                                  \
        lp_ = wave_red(lp_) + b2v;                                             \
        float link_ = (EK > 0) ? lp_ : -10000.0f;                              \
        if (lane == 0) {                                                       \
            smu[CK] = mu_; srs[CK] = rstd_; ssc[CK] = link_;                   \
            out_link[bs * CC + CK] = link_;                                    \
        }                                                                      \
    } while (0)

    CAND_TAIL(0, c0, e0, p0);
    CAND_TAIL(1, c1, e1, p1);
    CAND_TAIL(2, c2, e2, p2);
    if (has3) CAND_TAIL(3, c3, e3, p3);
    __syncthreads();

    if (tid < CC) {
        float m = ssc[0];
        #pragma unroll
        for (int c = 1; c < CC; ++c) m = fmaxf(m, ssc[c]);
        sexp[tid] = expf(ssc[tid] - m);
    }
    __syncthreads();

    const int d = tid;
    if (d < DENT) {
        float den = 0.f;
        #pragma unroll
        for (int c = 0; c < CC; ++c) den += sexp[c];
        const float inv = 1.f / den;
        float acc = 0.f, S2 = 0.f, sn = 0.f;
        #pragma unroll
        for (int c = 0; c < CC; ++c) {
            float n = sexp[c] * inv;
            float coef = n * srs[c];
            acc = fmaf(coef, rows[c][d], acc);
            S2 = fmaf(coef, smu[c], S2);
            sn += n;
        }
        out_w[(size_t)bs * DENT + d] = kg_g[d] * (acc - S2) + kg_b[d] * sn;
    }
}

extern "C" void kernel_launch(void* const* d_in, const int* in_sizes, int n_in,
                              void* d_out, int out_size, void* d_ws, size_t ws_size,
                              hipStream_t stream) {
    const float* ctx    = (const float*)d_in[0];
    const int*   spans  = (const int*)d_in[2];
    const int*   cand   = (const int*)d_in[3];
    const float* priors = (const float*)d_in[4];
    const float* table  = (const float*)d_in[6];
    const float* projW  = (const float*)d_in[7];
    const float* projb  = (const float*)d_in[8];
    const float* kg_g   = (const float*)d_in[9];
    const float* kg_b   = (const float*)d_in[10];
    const float* ln_g   = (const float*)d_in[11];
    const float* ln_b   = (const float*)d_in[12];
    const float* attW   = (const float*)d_in[13];
    const float* attb   = (const float*)d_in[14];
    const float* W1     = (const float*)d_in[15];
    const float* b1     = (const float*)d_in[16];
    const float* W2     = (const float*)d_in[17];
    const float* b2     = (const float*)d_in[18];

    float* proj = (float*)d_ws;                           // (B*T, 300)
    float* srg  = proj + (size_t)BB * TT * DENT;          // (B*S, 300)
    float* sgsb = srg + (size_t)BB * SS * DENT;           // (B*S, 2)
    // wpre (492 KB) aliases srg: consumed by gemm before span writes srg.
    ushort* wpre = (ushort*)srg;

    float* out_link = (float*)d_out;                      // (B*S*30)
    float* out_w    = out_link + (size_t)BB * SS * CC;    // (B*S, 300)

    wpre_kernel<<<NCT * NK * 64 / 256, 256, 0, stream>>>(projW, wpre);
    gemm_proj_mfma<<<BB * TT / GBM, 512, 0, stream>>>(ctx, wpre, projb, proj);
    span_kernel<<<BB * SS / 4, 256, 0, stream>>>(proj, spans, attW, attb,
                                                 ln_g, ln_b, kg_g, kg_b, srg, sgsb);
    final_fused<<<BB * SS, 512, 0, stream>>>(srg, sgsb, cand, priors, table,
                                             W1, b1, W2, b2, kg_g, kg_b,
                                             out_link, out_w);
}